// Round 1
// baseline (254.217 us; speedup 1.0000x reference)
//
#include <hip/hip_runtime.h>

#define U_CNT 16384
#define I_CNT 8192
#define DIM 64

typedef __bf16 bf16x8 __attribute__((ext_vector_type(8)));
typedef float f32x4 __attribute__((ext_vector_type(4)));

__device__ __forceinline__ unsigned short f32_to_bf16_rtn(float f) {
    unsigned int b = __float_as_uint(f);
    b += 0x7fffu + ((b >> 16) & 1u);
    return (unsigned short)(b >> 16);
}

// One wave per user: binary-search segment bounds, sum Q2 rows (lane = dim),
// scale by rsqrt(count), add P, write bf16.
__global__ __launch_bounds__(256) void pfull_kernel(
    const float* __restrict__ Q2, const float* __restrict__ P,
    const int* __restrict__ items, const int* __restrict__ segs,
    int nnz, unsigned short* __restrict__ Pbf)
{
    int gw = (blockIdx.x * 256 + threadIdx.x) >> 6;
    int lane = threadIdx.x & 63;
    if (gw >= U_CNT) return;
    int u = gw;
    int lo = 0, hi = nnz;
    while (lo < hi) { int m = (lo + hi) >> 1; if (segs[m] < u) lo = m + 1; else hi = m; }
    int start = lo;
    hi = nnz;
    while (lo < hi) { int m = (lo + hi) >> 1; if (segs[m] <= u) lo = m + 1; else hi = m; }
    int end = lo;
    float s = 0.f;
    for (int j = start; j < end; ++j) {
        int it = items[j];
        s += Q2[it * DIM + lane];
    }
    int cnt = end - start;              // guaranteed >= 1
    float val = s * rsqrtf((float)cnt) + P[u * DIM + lane];
    Pbf[u * DIM + lane] = f32_to_bf16_rtn(val);
}

__global__ __launch_bounds__(256) void q1conv_kernel(const float* __restrict__ Q1,
                                                     unsigned short* __restrict__ Q1bf)
{
    int i = blockIdx.x * 256 + threadIdx.x;   // exactly I_CNT*DIM threads
    Q1bf[i] = f32_to_bf16_rtn(Q1[i]);
}

// Block tile 64(M) x 128(N), 4 waves in 2x2; wave tile 32x64 = 2x4 fragments
// of 16x16, K=64 via two 16x16x32 MFMA k-steps. No LDS: A/B are 3 MB total,
// L2-resident; fragments loaded directly from global.
// A frag: lane holds A[row = lane%16][k = 8*(lane/16)+i], i=0..7 (16B contig).
// B frag: lane holds B[k][col = lane%16] = Q1[col][k] (same 16B contig load).
// C/D (verified): col = lane&15, row = (lane>>4)*4 + reg.
__global__ __launch_bounds__(256) void gemm_sig_kernel(
    const unsigned short* __restrict__ Abf, const unsigned short* __restrict__ Bbf,
    const float* __restrict__ bu, const float* __restrict__ bi,
    float* __restrict__ out)
{
    const int lane = threadIdx.x & 63;
    const int wid  = threadIdx.x >> 6;
    const int wm = wid >> 1, wn = wid & 1;
    const int bn0 = blockIdx.x * 128;
    const int bm0 = blockIdx.y * 64;
    const int r = lane & 15, g = lane >> 4;

    bf16x8 a[2][2], b[4][2];
#pragma unroll
    for (int mf = 0; mf < 2; ++mf)
#pragma unroll
        for (int ks = 0; ks < 2; ++ks) {
            int row = bm0 + wm * 32 + mf * 16 + r;
            a[mf][ks] = *reinterpret_cast<const bf16x8*>(&Abf[row * DIM + ks * 32 + g * 8]);
        }
#pragma unroll
    for (int nf = 0; nf < 4; ++nf)
#pragma unroll
        for (int ks = 0; ks < 2; ++ks) {
            int col = bn0 + wn * 64 + nf * 16 + r;
            b[nf][ks] = *reinterpret_cast<const bf16x8*>(&Bbf[col * DIM + ks * 32 + g * 8]);
        }

    f32x4 acc[2][4] = {};
#pragma unroll
    for (int ks = 0; ks < 2; ++ks)
#pragma unroll
        for (int mf = 0; mf < 2; ++mf)
#pragma unroll
            for (int nf = 0; nf < 4; ++nf)
                acc[mf][nf] = __builtin_amdgcn_mfma_f32_16x16x32_bf16(
                    a[mf][ks], b[nf][ks], acc[mf][nf], 0, 0, 0);

#pragma unroll
    for (int mf = 0; mf < 2; ++mf)
#pragma unroll
        for (int nf = 0; nf < 4; ++nf) {
            int col = bn0 + wn * 64 + nf * 16 + r;
            float bic = bi[col];
#pragma unroll
            for (int j = 0; j < 4; ++j) {
                int row = bm0 + wm * 32 + mf * 16 + g * 4 + j;
                float x = acc[mf][nf][j] + bu[row] + bic + 0.05f;
                out[(size_t)row * I_CNT + col] =
                    5.f * __builtin_amdgcn_rcpf(1.f + __expf(-x));
            }
        }
}

extern "C" void kernel_launch(void* const* d_in, const int* in_sizes, int n_in,
                              void* d_out, int out_size, void* d_ws, size_t ws_size,
                              hipStream_t stream)
{
    const float* Q1 = (const float*)d_in[0];
    const float* Q2 = (const float*)d_in[1];
    const float* P  = (const float*)d_in[2];
    const float* bu = (const float*)d_in[3];
    const float* bi = (const float*)d_in[4];
    const int* items = (const int*)d_in[5];
    const int* segs  = (const int*)d_in[6];
    const int nnz = in_sizes[5];

    unsigned short* Pbf  = (unsigned short*)d_ws;           // 16384*64*2 = 2 MB
    unsigned short* Q1bf = Pbf + U_CNT * DIM;               // 8192*64*2  = 1 MB

    pfull_kernel<<<U_CNT / 4, 256, 0, stream>>>(Q2, P, items, segs, nnz, Pbf);
    q1conv_kernel<<<(I_CNT * DIM) / 256, 256, 0, stream>>>(Q1, Q1bf);
    gemm_sig_kernel<<<dim3(I_CNT / 128, U_CNT / 64), 256, 0, stream>>>(
        Pbf, Q1bf, bu, bi, (float*)d_out);
}

// Round 2
// 232.872 us; speedup vs baseline: 1.0917x; 1.0917x over previous
//
#include <hip/hip_runtime.h>

#define U_CNT 16384
#define I_CNT 8192
#define DIM 64
#define BAND 16                   // output rows per gemm block
#define CHUNK 256                 // output cols per chunk iteration
#define NCHUNK (I_CNT / CHUNK)    // 32
#define LDS_STRIDE 68             // floats; 68 % 32 == 4 -> 2-way write conflict (free)

typedef __bf16 bf16x8 __attribute__((ext_vector_type(8)));
typedef float f32x4 __attribute__((ext_vector_type(4)));

__device__ __forceinline__ unsigned short f32_to_bf16_rtn(float f) {
    unsigned int b = __float_as_uint(f);
    b += 0x7fffu + ((b >> 16) & 1u);
    return (unsigned short)(b >> 16);
}

// One wave per user: binary-search segment bounds, sum Q2 rows (lane = dim),
// scale by rsqrt(count), add P, write bf16. Gather unrolled x4 to keep 4
// row-loads in flight (breaks the serial latency chain).
__global__ __launch_bounds__(256) void pfull_kernel(
    const float* __restrict__ Q2, const float* __restrict__ P,
    const int* __restrict__ items, const int* __restrict__ segs,
    int nnz, unsigned short* __restrict__ Pbf)
{
    int gw = (blockIdx.x * 256 + threadIdx.x) >> 6;
    int lane = threadIdx.x & 63;
    if (gw >= U_CNT) return;
    int u = gw;
    int lo = 0, hi = nnz;
    while (lo < hi) { int m = (lo + hi) >> 1; if (segs[m] < u) lo = m + 1; else hi = m; }
    int start = lo;
    hi = nnz;
    while (lo < hi) { int m = (lo + hi) >> 1; if (segs[m] <= u) lo = m + 1; else hi = m; }
    int end = lo;

    float s = 0.f;
    int j = start;
    for (; j + 3 < end; j += 4) {
        int i0 = items[j], i1 = items[j + 1], i2 = items[j + 2], i3 = items[j + 3];
        float v0 = Q2[i0 * DIM + lane];
        float v1 = Q2[i1 * DIM + lane];
        float v2 = Q2[i2 * DIM + lane];
        float v3 = Q2[i3 * DIM + lane];
        s += (v0 + v1) + (v2 + v3);
    }
    for (; j < end; ++j) s += Q2[items[j] * DIM + lane];

    int cnt = end - start;              // guaranteed >= 1
    float val = s * rsqrtf((float)cnt) + P[u * DIM + lane];
    Pbf[u * DIM + lane] = f32_to_bf16_rtn(val);
}

__global__ __launch_bounds__(256) void q1conv_kernel(const float* __restrict__ Q1,
                                                     unsigned short* __restrict__ Q1bf)
{
    int i = blockIdx.x * 256 + threadIdx.x;   // exactly I_CNT*DIM threads
    Q1bf[i] = f32_to_bf16_rtn(Q1[i]);
}

// Band-sweep GEMM + sigmoid epilogue.
// Block = 16-row band x full 8192 cols, swept in 32 chunks of 256 cols.
// 4 waves; wave wid owns cols [chunk*256 + wid*64, +64). Every output row is
// written by exactly ONE block, strictly left-to-right, as full-line float4
// stores (1 KB contiguous per wave-instruction) -> quasi-linear per-XCD HBM
// write streams instead of cross-XCD 512B scatter.
// MFMA 16x16x32_bf16; A frag: row=lane%16, k=ks*32+(lane/16)*8+i;
// B frag: col=lane%16 (Q1 row-major, k contiguous); C/D: col=lane&15,
// row=(lane>>4)*4+reg (verified by round-1 pass).
__global__ __launch_bounds__(256, 4) void gemm_sig_kernel(
    const unsigned short* __restrict__ Abf, const unsigned short* __restrict__ Bbf,
    const float* __restrict__ bu, const float* __restrict__ bi,
    float* __restrict__ out)
{
    const int lane = threadIdx.x & 63;
    const int wid  = threadIdx.x >> 6;      // 0..3: 64-col sub-band within chunk
    const int r = lane & 15, g = lane >> 4;
    const int band = blockIdx.x * BAND;

    __shared__ float lds_all[4][BAND * LDS_STRIDE];
    float* lds = lds_all[wid];              // per-wave private region: no barriers

    // A fragments for the whole band (rows band..band+15), both K-steps.
    bf16x8 a[2];
#pragma unroll
    for (int ks = 0; ks < 2; ++ks)
        a[ks] = *reinterpret_cast<const bf16x8*>(&Abf[(band + r) * DIM + ks * 32 + g * 8]);

    // bu for the 4 rows this lane will store (row = i*4 + g).
    float bu_r[4];
#pragma unroll
    for (int i = 0; i < 4; ++i) bu_r[i] = bu[band + i * 4 + g];

    for (int c = 0; c < NCHUNK; ++c) {
        const int col0 = c * CHUNK + wid * 64;

        bf16x8 b[4][2];
#pragma unroll
        for (int nf = 0; nf < 4; ++nf)
#pragma unroll
            for (int ks = 0; ks < 2; ++ks)
                b[nf][ks] = *reinterpret_cast<const bf16x8*>(
                    &Bbf[(col0 + nf * 16 + r) * DIM + ks * 32 + g * 8]);

        f32x4 acc[4] = {};
#pragma unroll
        for (int ks = 0; ks < 2; ++ks)
#pragma unroll
            for (int nf = 0; nf < 4; ++nf)
                acc[nf] = __builtin_amdgcn_mfma_f32_16x16x32_bf16(
                    a[ks], b[nf][ks], acc[nf], 0, 0, 0);

        // Transpose the wave's 16x64 tile through private LDS.
        // write: lds[row= g*4+j][col= nf*16+r]
#pragma unroll
        for (int nf = 0; nf < 4; ++nf)
#pragma unroll
            for (int j = 0; j < 4; ++j)
                lds[(g * 4 + j) * LDS_STRIDE + nf * 16 + r] = acc[nf][j];

        // Drain DS ops (same-wave cross-lane exchange; DS completes in order,
        // the asm is also a compiler reorder fence).
        __asm__ volatile("s_waitcnt lgkmcnt(0)" ::: "memory");

        // read back row-major: instr i covers rows i*4..i*4+3 (lane>>4 picks
        // row, lane&15 picks 16B col slot) -> 1KB contiguous per instruction.
#pragma unroll
        for (int i = 0; i < 4; ++i) {
            const int row = i * 4 + g;
            f32x4 v = *reinterpret_cast<const f32x4*>(&lds[row * LDS_STRIDE + r * 4]);
            f32x4 bv = *reinterpret_cast<const f32x4*>(&bi[col0 + r * 4]);
            f32x4 o;
#pragma unroll
            for (int k = 0; k < 4; ++k) {
                float x = v[k] + bu_r[i] + bv[k] + 0.05f;
                o[k] = 5.f * __builtin_amdgcn_rcpf(1.f + __expf(-x));
            }
            *reinterpret_cast<f32x4*>(
                &out[(size_t)(band + row) * I_CNT + col0 + r * 4]) = o;
        }
    }
}

extern "C" void kernel_launch(void* const* d_in, const int* in_sizes, int n_in,
                              void* d_out, int out_size, void* d_ws, size_t ws_size,
                              hipStream_t stream)
{
    const float* Q1 = (const float*)d_in[0];
    const float* Q2 = (const float*)d_in[1];
    const float* P  = (const float*)d_in[2];
    const float* bu = (const float*)d_in[3];
    const float* bi = (const float*)d_in[4];
    const int* items = (const int*)d_in[5];
    const int* segs  = (const int*)d_in[6];
    const int nnz = in_sizes[5];

    unsigned short* Pbf  = (unsigned short*)d_ws;           // 16384*64*2 = 2 MB
    unsigned short* Q1bf = Pbf + U_CNT * DIM;               // 8192*64*2  = 1 MB

    pfull_kernel<<<U_CNT / 4, 256, 0, stream>>>(Q2, P, items, segs, nnz, Pbf);
    q1conv_kernel<<<(I_CNT * DIM) / 256, 256, 0, stream>>>(Q1, Q1bf);
    gemm_sig_kernel<<<U_CNT / BAND, 256, 0, stream>>>(Pbf, Q1bf, bu, bi, (float*)d_out);
}

// Round 3
// 185.847 us; speedup vs baseline: 1.3679x; 1.2530x over previous
//
#include <hip/hip_runtime.h>

#define U_CNT 16384
#define I_CNT 8192
#define DIM 64
#define BAND 16                   // output rows per gemm block
#define CHUNK 256                 // output cols per chunk iteration
#define NCHUNK (I_CNT / CHUNK)    // 32
#define LDS_STRIDE 68             // floats; 68 % 32 == 4 -> 2-way conflicts only (free)

typedef __bf16 bf16x8 __attribute__((ext_vector_type(8)));
typedef float f32x4 __attribute__((ext_vector_type(4)));

__device__ __forceinline__ unsigned short f32_to_bf16_rtn(float f) {
    unsigned int b = __float_as_uint(f);
    b += 0x7fffu + ((b >> 16) & 1u);
    return (unsigned short)(b >> 16);
}

// Fused prep: blocks [0, 2048) convert Q1 -> bf16; blocks [2048, 6144) scan
// seg_ids for segment boundaries (every user has >=1 item, so every
// bounds[u] gets exactly one write; bounds[U_CNT] = nnz).
__global__ __launch_bounds__(256) void prep_kernel(
    const float* __restrict__ Q1, unsigned short* __restrict__ Q1bf,
    const int* __restrict__ segs, int nnz, int* __restrict__ bounds)
{
    if (blockIdx.x < 2048) {
        int i = blockIdx.x * 256 + threadIdx.x;   // covers I_CNT*DIM = 524288
        Q1bf[i] = f32_to_bf16_rtn(Q1[i]);
    } else {
        int i = (blockIdx.x - 2048) * 256 + threadIdx.x;
        if (i >= nnz) return;
        if (i == 0) bounds[segs[0]] = 0;
        else if (segs[i] != segs[i - 1]) bounds[segs[i]] = i;
        if (i == nnz - 1) bounds[U_CNT] = nnz;
    }
}

// One wave per user: read precomputed bounds (no binary search), sum Q2 rows
// (lane = dim), scale by rsqrt(count), add P, write bf16. Gather unrolled x4.
__global__ __launch_bounds__(256) void pfull_kernel(
    const float* __restrict__ Q2, const float* __restrict__ P,
    const int* __restrict__ items, const int* __restrict__ bounds,
    unsigned short* __restrict__ Pbf)
{
    int u = (blockIdx.x * 256 + threadIdx.x) >> 6;
    int lane = threadIdx.x & 63;
    if (u >= U_CNT) return;
    int start = bounds[u];
    int end   = bounds[u + 1];

    float s = 0.f;
    int j = start;
    for (; j + 3 < end; j += 4) {
        int i0 = items[j], i1 = items[j + 1], i2 = items[j + 2], i3 = items[j + 3];
        float v0 = Q2[i0 * DIM + lane];
        float v1 = Q2[i1 * DIM + lane];
        float v2 = Q2[i2 * DIM + lane];
        float v3 = Q2[i3 * DIM + lane];
        s += (v0 + v1) + (v2 + v3);
    }
    for (; j < end; ++j) s += Q2[items[j] * DIM + lane];

    int cnt = end - start;              // guaranteed >= 1
    float val = s * rsqrtf((float)cnt) + P[u * DIM + lane];
    Pbf[u * DIM + lane] = f32_to_bf16_rtn(val);
}

// Band-sweep GEMM + sigmoid epilogue.
// Block = 16-row band x all 8192 cols, swept in 32 chunks of 256 cols; wave
// wid owns a 64-col sub-band of each chunk. Chunk order is PHASE-STAGGERED
// per block ((blockIdx*7)&31) so concurrent blocks write uniformly across the
// full row width -> all HBM channels active (lockstep sweep concentrated all
// 16k streams on one 1KB-mod-32KB stripe = few channels).
// Sigmoid applied in acc layout (row=g*4+j, col=nf*16+r) BEFORE the private
// per-wave LDS transpose; post-transpose work is ds_read + f32x4 store only.
// No barriers, no inline-asm fences -> compiler free to pipeline chunks.
__global__ __launch_bounds__(256) void gemm_sig_kernel(
    const unsigned short* __restrict__ Abf, const unsigned short* __restrict__ Bbf,
    const float* __restrict__ bu, const float* __restrict__ bi,
    float* __restrict__ out)
{
    const int lane = threadIdx.x & 63;
    const int wid  = threadIdx.x >> 6;      // 0..3: 64-col sub-band within chunk
    const int r = lane & 15, g = lane >> 4;
    const int band = blockIdx.x * BAND;

    __shared__ float lds_all[4][BAND * LDS_STRIDE];
    float* lds = lds_all[wid];              // per-wave private region

    // A fragments for the whole band (rows band..band+15), both K-steps.
    bf16x8 a[2];
#pragma unroll
    for (int ks = 0; ks < 2; ++ks)
        a[ks] = *reinterpret_cast<const bf16x8*>(&Abf[(band + r) * DIM + ks * 32 + g * 8]);

    // bu for the 4 acc rows this lane holds (row = g*4 + j).
    float bu_g[4];
#pragma unroll
    for (int j = 0; j < 4; ++j) bu_g[j] = bu[band + g * 4 + j];

    const int c0 = (blockIdx.x * 7) & (NCHUNK - 1);

    for (int cc = 0; cc < NCHUNK; ++cc) {
        const int c = (cc + c0) & (NCHUNK - 1);
        const int col0 = c * CHUNK + wid * 64;

        bf16x8 b[4][2];
        float bi_f[4];
#pragma unroll
        for (int nf = 0; nf < 4; ++nf) {
            bi_f[nf] = bi[col0 + nf * 16 + r];
#pragma unroll
            for (int ks = 0; ks < 2; ++ks)
                b[nf][ks] = *reinterpret_cast<const bf16x8*>(
                    &Bbf[(col0 + nf * 16 + r) * DIM + ks * 32 + g * 8]);
        }

        f32x4 acc[4] = {};
#pragma unroll
        for (int ks = 0; ks < 2; ++ks)
#pragma unroll
            for (int nf = 0; nf < 4; ++nf)
                acc[nf] = __builtin_amdgcn_mfma_f32_16x16x32_bf16(
                    a[ks], b[nf][ks], acc[nf], 0, 0, 0);

        // Sigmoid in acc layout, then transpose finished values through LDS.
#pragma unroll
        for (int nf = 0; nf < 4; ++nf)
#pragma unroll
            for (int j = 0; j < 4; ++j) {
                float x = acc[nf][j] + bu_g[j] + bi_f[nf] + 0.05f;
                float v = 5.f * __builtin_amdgcn_rcpf(1.f + __expf(-x));
                lds[(g * 4 + j) * LDS_STRIDE + nf * 16 + r] = v;
            }

        // Read back row-major (compiler inserts the lgkmcnt wait): instr i
        // covers rows i*4..i*4+3, 256B contiguous per row, full cache lines.
#pragma unroll
        for (int i = 0; i < 4; ++i) {
            const int row = i * 4 + g;
            f32x4 v = *reinterpret_cast<const f32x4*>(&lds[row * LDS_STRIDE + r * 4]);
            *reinterpret_cast<f32x4*>(
                &out[(size_t)(band + row) * I_CNT + col0 + r * 4]) = v;
        }
    }
}

extern "C" void kernel_launch(void* const* d_in, const int* in_sizes, int n_in,
                              void* d_out, int out_size, void* d_ws, size_t ws_size,
                              hipStream_t stream)
{
    const float* Q1 = (const float*)d_in[0];
    const float* Q2 = (const float*)d_in[1];
    const float* P  = (const float*)d_in[2];
    const float* bu = (const float*)d_in[3];
    const float* bi = (const float*)d_in[4];
    const int* items = (const int*)d_in[5];
    const int* segs  = (const int*)d_in[6];
    const int nnz = in_sizes[5];

    unsigned short* Pbf  = (unsigned short*)d_ws;            // 2 MB
    unsigned short* Q1bf = Pbf + U_CNT * DIM;                // 1 MB
    int* bounds = (int*)(Q1bf + I_CNT * DIM);                // 64 KB + 4

    int boundsBlocks = (nnz + 255) / 256;                    // 4096 for nnz=1M
    prep_kernel<<<2048 + boundsBlocks, 256, 0, stream>>>(Q1, Q1bf, segs, nnz, bounds);
    pfull_kernel<<<U_CNT / 4, 256, 0, stream>>>(Q2, P, items, bounds, Pbf);
    gemm_sig_kernel<<<U_CNT / BAND, 256, 0, stream>>>(Pbf, Q1bf, bu, bi, (float*)d_out);
}